// Round 1
// baseline (5367.900 us; speedup 1.0000x reference)
//
#include <hip/hip_runtime.h>

typedef unsigned short u16;
typedef __attribute__((ext_vector_type(8))) short bf16x8;
typedef __attribute__((ext_vector_type(4))) float f32x4;

#define DEV __device__ __forceinline__

DEV float bf2f(u16 u) { unsigned v = ((unsigned)u) << 16; float f; __builtin_memcpy(&f, &v, 4); return f; }
DEV u16 f2bf(float f) { unsigned u; __builtin_memcpy(&u, &f, 4); u += 0x7FFFu + ((u >> 16) & 1u); return (u16)(u >> 16); }
DEV float sigm(float x) { return 1.f / (1.f + __expf(-x)); }
DEV float tanha(float x) { x = fminf(9.f, fmaxf(-9.f, x)); float t = __expf(2.f * x); return (t - 1.f) / (t + 1.f); }

#define NBLK 192

// ---------------- grid barrier (agent-scope release/acquire + atomic counter) ----
DEV void grid_bar(unsigned* bar, unsigned target) {
    __syncthreads();
    if (threadIdx.x == 0) {
        __builtin_amdgcn_fence(__ATOMIC_RELEASE, "agent");
        __hip_atomic_fetch_add(bar, 1u, __ATOMIC_RELAXED, __HIP_MEMORY_SCOPE_AGENT);
        long long guard = 0;
        while (__hip_atomic_load(bar, __ATOMIC_RELAXED, __HIP_MEMORY_SCOPE_AGENT) < target) {
            __builtin_amdgcn_s_sleep(2);
            if (++guard > (1LL << 24)) break;  // safety net, never fires legitimately
        }
        __builtin_amdgcn_fence(__ATOMIC_ACQUIRE, "agent");
    }
    __syncthreads();
}

// ---------------- converts / init ----------------
__global__ __launch_bounds__(256) void cvt_kernel(const float* __restrict__ s, u16* __restrict__ d, long long n) {
    long long i = ((long long)blockIdx.x * 256 + threadIdx.x) * 4;
    if (i < n) {
        float4 v = *(const float4*)(s + i);
        uint2 o;
        o.x = (unsigned)f2bf(v.x) | ((unsigned)f2bf(v.y) << 16);
        o.y = (unsigned)f2bf(v.z) | ((unsigned)f2bf(v.w) << 16);
        *(uint2*)(d + i) = o;
    }
}

__global__ __launch_bounds__(256) void cvt_wout_kernel(const float* __restrict__ s, u16* __restrict__ d) {
    long long i = ((long long)blockIdx.x * 256 + threadIdx.x) * 4;  // over 8192*1024
    int row = (int)(i >> 10), col = (int)(i & 1023);
    uint2 o;
    if (row < 8000) {
        float4 v = *(const float4*)(s + (size_t)row * 1024 + col);
        o.x = (unsigned)f2bf(v.x) | ((unsigned)f2bf(v.y) << 16);
        o.y = (unsigned)f2bf(v.z) | ((unsigned)f2bf(v.w) << 16);
    } else { o.x = 0u; o.y = 0u; }
    *(uint2*)(d + i) = o;
}

__global__ __launch_bounds__(256) void badd_kernel(const float* __restrict__ a, const float* __restrict__ b,
                                                   float* __restrict__ o, int n) {
    int i = blockIdx.x * 256 + threadIdx.x;
    if (i < n) o[i] = a[i] + b[i];
}

__global__ __launch_bounds__(256) void init_kernel(const float* __restrict__ h0, u16* __restrict__ h1buf,
                                                   u16* __restrict__ h2buf, unsigned* __restrict__ bar) {
    int i = blockIdx.x * 256 + threadIdx.x;  // 65536 total
    if (i < 65536) {
        h1buf[65536 + i] = f2bf(h0[i]);  // h1_state(-1) = h0  (parity buffer 1)
        h2buf[65536 + i] = 0;            // h2_state(-1) = 0
    }
    if (i == 0) *bar = 0u;
}

// ---------------- generic 64x256-tile bf16 GEMM (C = A @ B^T + bias) ----------------
// MODE 0: phase A. A-row b of tile t = emb_bf[gt[b*256+t]] (K=512). out: bf16 X1[(t*64+b)*4096 + n].
// MODE 1: phase C. A-row = H2[(t*64+row)*1024] (K=1024). out: f32 out[(ml*255+t)*8000 + n], n<8000.
template <int MODE, int K>
__global__ __launch_bounds__(256) void gemm_kernel(const u16* __restrict__ Asrc, const u16* __restrict__ Bmat,
                                                   const int* __restrict__ gt, const float* __restrict__ bias,
                                                   void* __restrict__ outp) {
    __shared__ uint4 AldsV[512];   // 64 x 64 bf16 = 8 KiB
    __shared__ uint4 BldsV[2048];  // 256 x 64 bf16 = 32 KiB
    char* Al = (char*)AldsV;
    char* Bl = (char*)BldsV;
    const int t = blockIdx.y;
    const int n0 = blockIdx.x << 8;
    const int tid = threadIdx.x;
    const int lane = tid & 63, wid = tid >> 6;

    f32x4 acc[4][4] = {};

    for (int k0 = 0; k0 < K; k0 += 64) {
        // stage A-tile: 512 chunks of 16B
#pragma unroll
        for (int q = 0; q < 2; ++q) {
            int c = tid + (q << 8);
            int row = c >> 3, kc = c & 7;
            const u16* src;
            if (MODE == 0) {
                int tok = gt[row * 256 + t];
                src = Asrc + (size_t)tok * 512 + (k0 + (kc << 3));
            } else {
                src = Asrc + ((size_t)((t << 6) + row) << 10) + (k0 + (kc << 3));
            }
            *(uint4*)(Al + row * 128 + ((kc ^ (row & 7)) << 4)) = *(const uint4*)src;
        }
        // stage B-tile: 2048 chunks
#pragma unroll
        for (int q = 0; q < 8; ++q) {
            int c = tid + (q << 8);
            int row = c >> 3, kc = c & 7;
            *(uint4*)(Bl + row * 128 + ((kc ^ (row & 7)) << 4)) =
                *(const uint4*)(Bmat + (size_t)(n0 + row) * K + (k0 + (kc << 3)));
        }
        __syncthreads();
#pragma unroll
        for (int kb2 = 0; kb2 < 2; ++kb2) {
            bf16x8 af[4], bf[4];
#pragma unroll
            for (int mt = 0; mt < 4; ++mt) {
                int row = (mt << 4) + (lane & 15);
                int kc = (kb2 << 2) + (lane >> 4);
                af[mt] = *(const bf16x8*)(Al + row * 128 + ((kc ^ (row & 7)) << 4));
            }
#pragma unroll
            for (int nt = 0; nt < 4; ++nt) {
                int row = (wid << 6) + (nt << 4) + (lane & 15);
                int kc = (kb2 << 2) + (lane >> 4);
                bf[nt] = *(const bf16x8*)(Bl + row * 128 + ((kc ^ (row & 7)) << 4));
            }
#pragma unroll
            for (int mt = 0; mt < 4; ++mt)
#pragma unroll
                for (int nt = 0; nt < 4; ++nt)
                    acc[mt][nt] = __builtin_amdgcn_mfma_f32_16x16x32_bf16(af[mt], bf[nt], acc[mt][nt], 0, 0, 0);
        }
        __syncthreads();
    }

    // epilogue (C/D layout: col = lane&15, row = (lane>>4)*4 + r)
#pragma unroll
    for (int nt = 0; nt < 4; ++nt) {
        int n = n0 + (wid << 6) + (nt << 4) + (lane & 15);
        float bv = 0.f;
        if (MODE == 0) bv = bias[n];
        else if (n < 8000) bv = bias[n];
#pragma unroll
        for (int mt = 0; mt < 4; ++mt) {
#pragma unroll
            for (int r = 0; r < 4; ++r) {
                int ml = (mt << 4) + ((lane >> 4) << 2) + r;
                float v = acc[mt][nt][r] + bv;
                if (MODE == 0) {
                    ((u16*)outp)[((size_t)((t << 6) + ml) << 12) + n] = f2bf(v);
                } else {
                    if (n < 8000) ((float*)outp)[(size_t)(ml * 255 + t) * 8000 + n] = v;
                }
            }
        }
    }
}

// ---------------- persistent pipelined 2-layer LSTM (cooperative) ----------------
// blocks 0..63  : layer1, 16 h-columns each (j0=bid*16), K=1024, computes h1_state(i) at iter i (i<=254)
// blocks 64..191: layer2, 8 h-columns each,              K=2048, computes h2_state(i-1) at iter i (i>=1)
// one grid barrier per iteration.
__global__ __launch_bounds__(256) void lstm_kernel(const u16* __restrict__ X1, const float* __restrict__ c0,
                                                   u16* __restrict__ h1buf, u16* __restrict__ h2buf,
                                                   u16* __restrict__ H2, const u16* __restrict__ Whh1,
                                                   const u16* __restrict__ Wih2, const u16* __restrict__ Whh2,
                                                   const float* __restrict__ b2, unsigned* __restrict__ bar) {
    __shared__ uint4 WldsV[8192];  // 128 KiB weight slice
    char* Wb = (char*)WldsV;
    const int tid = threadIdx.x;
    const int lane = tid & 63, wid = tid >> 6;
    const int bid = blockIdx.x;
    const bool L1 = (bid < 64);
    const int j0 = L1 ? (bid << 4) : ((bid - 64) << 3);

    // ---- stage weights into LDS (XOR-swizzled rows: 2-way max bank aliasing on b128 reads) ----
    if (L1) {
        // 64 rows (r = g*16 + jj) x 1024 k, row stride 2048B
#pragma unroll 8
        for (int q = 0; q < 32; ++q) {
            int c = tid + (q << 8);
            int row = c >> 7, kc = c & 127;
            int gcol = ((row >> 4) << 10) + j0 + (row & 15);
            uint4 v = *(const uint4*)(Whh1 + ((size_t)gcol << 10) + (kc << 3));
            *(uint4*)(Wb + row * 2048 + ((kc ^ (row & 7)) << 4)) = v;
        }
    } else {
        // 32 rows (r = g*8 + jj) x 2048 k (Wih2 | Whh2), row stride 4096B
#pragma unroll 8
        for (int q = 0; q < 32; ++q) {
            int c = tid + (q << 8);
            int row = c >> 8, kc = c & 255;
            int gcol = ((row >> 3) << 10) + j0 + (row & 7);
            const u16* src = (kc < 128) ? (Wih2 + ((size_t)gcol << 10) + (kc << 3))
                                        : (Whh2 + ((size_t)gcol << 10) + ((kc - 128) << 3));
            uint4 v = *(const uint4*)src;
            *(uint4*)(Wb + row * 4096 + ((kc ^ (row & 7)) << 4)) = v;
        }
    }

    // ---- per-lane persistent cell state ----
    float creg[4] = {0.f, 0.f, 0.f, 0.f};
    if (L1) {
        int jj = lane & 15;
#pragma unroll
        for (int r = 0; r < 4; ++r) {
            int b = (wid << 4) + ((lane >> 4) << 2) + r;
            creg[r] = c0[(b << 10) + j0 + jj];
        }
    }
    float b2v[4] = {0.f, 0.f, 0.f, 0.f};
    if (!L1 && (lane & 15) < 8) {
        int jj = lane & 7;
#pragma unroll
        for (int g = 0; g < 4; ++g) b2v[g] = b2[(g << 10) + j0 + jj];
    }
    __syncthreads();

    for (int i = 0; i < 256; ++i) {
        if (L1) {
            if (i < 255) {
                const u16* hp = h1buf + (((i + 1) & 1) << 16);  // h1_state(i-1)
                const int arow = (wid << 4) + (lane & 15);
                const u16* ab = hp + (arow << 10) + ((lane >> 4) << 3);
                f32x4 acc[4] = {};
#pragma unroll 4
                for (int kb = 0; kb < 32; ++kb) {
                    bf16x8 a = *(const bf16x8*)(ab + (kb << 5));
#pragma unroll
                    for (int g = 0; g < 4; ++g) {
                        int row = (g << 4) + (lane & 15);
                        int kc = (kb << 2) + (lane >> 4);
                        bf16x8 bfrag = *(const bf16x8*)(Wb + row * 2048 + ((kc ^ (row & 7)) << 4));
                        acc[g] = __builtin_amdgcn_mfma_f32_16x16x32_bf16(a, bfrag, acc[g], 0, 0, 0);
                    }
                }
                int jj = lane & 15;
                u16* hout = h1buf + ((i & 1) << 16);
#pragma unroll
                for (int r = 0; r < 4; ++r) {
                    int b = (wid << 4) + ((lane >> 4) << 2) + r;
                    const u16* xp = X1 + ((size_t)((i << 6) + b) << 12) + j0 + jj;
                    float gi = acc[0][r] + bf2f(xp[0]);
                    float gf = acc[1][r] + bf2f(xp[1024]);
                    float gg = acc[2][r] + bf2f(xp[2048]);
                    float go = acc[3][r] + bf2f(xp[3072]);
                    float cc = sigm(gf) * creg[r] + sigm(gi) * tanha(gg);
                    creg[r] = cc;
                    hout[(b << 10) + j0 + jj] = f2bf(sigm(go) * tanha(cc));
                }
            }
        } else {
            if (i >= 1) {
                const u16* hp1 = h1buf + (((i + 1) & 1) << 16);  // h1_state(i-1)
                const u16* hp2 = h2buf + ((i & 1) << 16);        // h2_state(i-2)
                const int arow = (wid << 4) + (lane & 15);
                const u16* ab1 = hp1 + (arow << 10) + ((lane >> 4) << 3);
                const u16* ab2 = hp2 + (arow << 10) + ((lane >> 4) << 3);
                f32x4 acc[2] = {};
#pragma unroll 4
                for (int kb = 0; kb < 32; ++kb) {
                    bf16x8 a = *(const bf16x8*)(ab1 + (kb << 5));
#pragma unroll
                    for (int nt = 0; nt < 2; ++nt) {
                        int row = (nt << 4) + (lane & 15);
                        int kc = (kb << 2) + (lane >> 4);
                        bf16x8 bfrag = *(const bf16x8*)(Wb + row * 4096 + ((kc ^ (row & 7)) << 4));
                        acc[nt] = __builtin_amdgcn_mfma_f32_16x16x32_bf16(a, bfrag, acc[nt], 0, 0, 0);
                    }
                }
#pragma unroll 4
                for (int kb = 32; kb < 64; ++kb) {
                    bf16x8 a = *(const bf16x8*)(ab2 + ((kb - 32) << 5));
#pragma unroll
                    for (int nt = 0; nt < 2; ++nt) {
                        int row = (nt << 4) + (lane & 15);
                        int kc = (kb << 2) + (lane >> 4);
                        bf16x8 bfrag = *(const bf16x8*)(Wb + row * 4096 + ((kc ^ (row & 7)) << 4));
                        acc[nt] = __builtin_amdgcn_mfma_f32_16x16x32_bf16(a, bfrag, acc[nt], 0, 0, 0);
                    }
                }
                // gates: lane jj<8 holds {i,g}, partner lane jj+8 holds {f,o} -> shfl_xor(8)
                int s = i - 1;
                u16* hout = h2buf + ((s & 1) << 16);
#pragma unroll
                for (int r = 0; r < 4; ++r) {
                    float v0 = acc[0][r], v1 = acc[1][r];
                    float p0 = __shfl_xor(v0, 8, 64);
                    float p1 = __shfl_xor(v1, 8, 64);
                    if ((lane & 15) < 8) {
                        int jj = lane & 7;
                        int b = (wid << 4) + ((lane >> 4) << 2) + r;
                        float gi = v0 + b2v[0];
                        float gf = p0 + b2v[1];
                        float gg = v1 + b2v[2];
                        float go = p1 + b2v[3];
                        float cc = sigm(gf) * creg[r] + sigm(gi) * tanha(gg);
                        creg[r] = cc;
                        u16 hb = f2bf(sigm(go) * tanha(cc));
                        hout[(b << 10) + j0 + jj] = hb;
                        H2[((size_t)((s << 6) + b) << 10) + j0 + jj] = hb;
                    }
                }
            }
        }
        grid_bar(bar, (unsigned)(NBLK * (i + 1)));
    }
}

// ---------------- per-row log-softmax, in-place on d_out ----------------
__global__ __launch_bounds__(256) void lsm_kernel(float* __restrict__ out) {
    float* p = out + (size_t)blockIdx.x * 8000;
    const int tid = threadIdx.x;
    float4 v[8];
    float mx = -3.0e38f;
#pragma unroll
    for (int q = 0; q < 8; ++q) {
        int vi = tid + (q << 8);
        if (vi < 2000) {
            v[q] = *((const float4*)p + vi);
            mx = fmaxf(mx, fmaxf(fmaxf(v[q].x, v[q].y), fmaxf(v[q].z, v[q].w)));
        }
    }
#pragma unroll
    for (int o = 32; o >= 1; o >>= 1) mx = fmaxf(mx, __shfl_xor(mx, o, 64));
    __shared__ float red[8];
    if ((tid & 63) == 0) red[tid >> 6] = mx;
    __syncthreads();
    mx = fmaxf(fmaxf(red[0], red[1]), fmaxf(red[2], red[3]));
    float s = 0.f;
#pragma unroll
    for (int q = 0; q < 8; ++q) {
        int vi = tid + (q << 8);
        if (vi < 2000)
            s += __expf(v[q].x - mx) + __expf(v[q].y - mx) + __expf(v[q].z - mx) + __expf(v[q].w - mx);
    }
#pragma unroll
    for (int o = 32; o >= 1; o >>= 1) s += __shfl_xor(s, o, 64);
    if ((tid & 63) == 0) red[4 + (tid >> 6)] = s;
    __syncthreads();
    float lz = mx + logf(red[4] + red[5] + red[6] + red[7]);
#pragma unroll
    for (int q = 0; q < 8; ++q) {
        int vi = tid + (q << 8);
        if (vi < 2000) {
            float4 o4;
            o4.x = v[q].x - lz; o4.y = v[q].y - lz; o4.z = v[q].z - lz; o4.w = v[q].w - lz;
            *((float4*)p + vi) = o4;
        }
    }
}

// ---------------- host launch ----------------
extern "C" void kernel_launch(void* const* d_in, const int* in_sizes, int n_in,
                              void* d_out, int out_size, void* d_ws, size_t ws_size,
                              hipStream_t stream) {
    const int* gt = (const int*)d_in[0];
    const float* h0 = (const float*)d_in[1];
    const float* c0 = (const float*)d_in[2];
    const float* emb = (const float*)d_in[3];
    const float* Wih1 = (const float*)d_in[4];
    const float* Whh1 = (const float*)d_in[5];
    const float* bih1 = (const float*)d_in[6];
    const float* bhh1 = (const float*)d_in[7];
    const float* Wih2 = (const float*)d_in[8];
    const float* Whh2 = (const float*)d_in[9];
    const float* bih2 = (const float*)d_in[10];
    const float* bhh2 = (const float*)d_in[11];
    const float* Wout = (const float*)d_in[12];
    const float* bout = (const float*)d_in[13];

    char* w = (char*)d_ws;
    size_t off = 0;
    auto alloc = [&](size_t bytes) -> void* {
        void* p = (void*)(w + off);
        off = (off + bytes + 255) & ~(size_t)255;
        return p;
    };
    unsigned* bar = (unsigned*)alloc(256);
    float* b1 = (float*)alloc(4096 * 4);
    float* b2 = (float*)alloc(4096 * 4);
    u16* h1buf = (u16*)alloc(2 * 65536 * 2);
    u16* h2buf = (u16*)alloc(2 * 65536 * 2);
    u16* embB = (u16*)alloc((size_t)8000 * 512 * 2);
    u16* Wih1B = (u16*)alloc((size_t)4096 * 512 * 2);
    u16* Whh1B = (u16*)alloc((size_t)4096 * 1024 * 2);
    u16* Wih2B = (u16*)alloc((size_t)4096 * 1024 * 2);
    u16* Whh2B = (u16*)alloc((size_t)4096 * 1024 * 2);
    u16* WoutB = (u16*)alloc((size_t)8192 * 1024 * 2);
    u16* H2 = (u16*)alloc((size_t)16320 * 1024 * 2);
    u16* X1 = (u16*)d_out;  // 134 MB staged inside d_out (dead until phase C overwrites)

    auto cvtN = [&](const float* s, u16* d, long long n) {
        unsigned blocks = (unsigned)((n / 4 + 255) / 256);
        cvt_kernel<<<blocks, 256, 0, stream>>>(s, d, n);
    };
    cvtN(emb, embB, (long long)8000 * 512);
    cvtN(Wih1, Wih1B, (long long)4096 * 512);
    cvtN(Whh1, Whh1B, (long long)4096 * 1024);
    cvtN(Wih2, Wih2B, (long long)4096 * 1024);
    cvtN(Whh2, Whh2B, (long long)4096 * 1024);
    cvt_wout_kernel<<<8192, 256, 0, stream>>>(Wout, WoutB);
    badd_kernel<<<16, 256, 0, stream>>>(bih1, bhh1, b1, 4096);
    badd_kernel<<<16, 256, 0, stream>>>(bih2, bhh2, b2, 4096);
    init_kernel<<<256, 256, 0, stream>>>(h0, h1buf, h2buf, bar);

    // phase A: X1 = emb[gt] @ Wih1^T + b1  (bf16, into d_out scratch)
    gemm_kernel<0, 512><<<dim3(16, 255), 256, 0, stream>>>(embB, Wih1B, gt, b1, (void*)X1);

    // phase B: persistent pipelined recurrence
    {
        void* args[] = {(void*)&X1, (void*)&c0, (void*)&h1buf, (void*)&h2buf, (void*)&H2,
                        (void*)&Whh1B, (void*)&Wih2B, (void*)&Whh2B, (void*)&b2, (void*)&bar};
        (void)hipLaunchCooperativeKernel(reinterpret_cast<const void*>(&lstm_kernel),
                                         dim3(NBLK), dim3(256), args, 0, stream);
    }

    // phase C: logits = H2 @ Wout^T + bout  (fp32 into d_out, (b,t,v) layout)
    gemm_kernel<1, 1024><<<dim3(32, 255), 256, 0, stream>>>(H2, WoutB, nullptr, bout, d_out);

    // log-softmax in place
    lsm_kernel<<<16320, 256, 0, stream>>>((float*)d_out);
}

// Round 2
// 4349.632 us; speedup vs baseline: 1.2341x; 1.2341x over previous
//
#include <hip/hip_runtime.h>

typedef unsigned short u16;
typedef unsigned long long u64;
typedef __attribute__((ext_vector_type(8))) short bf16x8;
typedef __attribute__((ext_vector_type(4))) float f32x4;

#define DEV __device__ __forceinline__

DEV float bf2f(u16 u) { unsigned v = ((unsigned)u) << 16; float f; __builtin_memcpy(&f, &v, 4); return f; }
DEV u16 f2bf(float f) { unsigned u; __builtin_memcpy(&u, &f, 4); u += 0x7FFFu + ((u >> 16) & 1u); return (u16)(u >> 16); }
DEV float sigm(float x) { return 1.f / (1.f + __expf(-x)); }
DEV float tanha(float x) { x = fminf(9.f, fmaxf(-9.f, x)); float t = __expf(2.f * x); return (t - 1.f) / (t + 1.f); }

#define NBLK 192

// ---------------- fence-free grid barrier (relaxed atomics only) ----------------
// h-state is made visible via sc1 write-through stores (agent-scope relaxed atomic
// stores) drained by vmcnt(0) before s_barrier; no L2 writeback/invalidate needed.
DEV void grid_bar(unsigned* bar, unsigned target) {
    __syncthreads();
    if (threadIdx.x == 0) {
        __hip_atomic_fetch_add(bar, 1u, __ATOMIC_RELAXED, __HIP_MEMORY_SCOPE_AGENT);
        long long guard = 0;
        while (__hip_atomic_load(bar, __ATOMIC_RELAXED, __HIP_MEMORY_SCOPE_AGENT) < target) {
            __builtin_amdgcn_s_sleep(2);
            if (++guard > (1LL << 24)) break;  // safety net, never fires legitimately
        }
    }
    __syncthreads();
}

// ---------------- converts / init ----------------
__global__ __launch_bounds__(256) void cvt_kernel(const float* __restrict__ s, u16* __restrict__ d, long long n) {
    long long i = ((long long)blockIdx.x * 256 + threadIdx.x) * 4;
    if (i < n) {
        float4 v = *(const float4*)(s + i);
        uint2 o;
        o.x = (unsigned)f2bf(v.x) | ((unsigned)f2bf(v.y) << 16);
        o.y = (unsigned)f2bf(v.z) | ((unsigned)f2bf(v.w) << 16);
        *(uint2*)(d + i) = o;
    }
}

__global__ __launch_bounds__(256) void cvt_wout_kernel(const float* __restrict__ s, u16* __restrict__ d) {
    long long i = ((long long)blockIdx.x * 256 + threadIdx.x) * 4;  // over 8192*1024
    int row = (int)(i >> 10), col = (int)(i & 1023);
    uint2 o;
    if (row < 8000) {
        float4 v = *(const float4*)(s + (size_t)row * 1024 + col);
        o.x = (unsigned)f2bf(v.x) | ((unsigned)f2bf(v.y) << 16);
        o.y = (unsigned)f2bf(v.z) | ((unsigned)f2bf(v.w) << 16);
    } else { o.x = 0u; o.y = 0u; }
    *(uint2*)(d + i) = o;
}

__global__ __launch_bounds__(256) void badd_kernel(const float* __restrict__ a, const float* __restrict__ b,
                                                   float* __restrict__ o, int n) {
    int i = blockIdx.x * 256 + threadIdx.x;
    if (i < n) o[i] = a[i] + b[i];
}

__global__ __launch_bounds__(256) void init_kernel(const float* __restrict__ h0, u16* __restrict__ h1ring,
                                                   u16* __restrict__ h2ring, unsigned* __restrict__ bar) {
    int i = blockIdx.x * 256 + threadIdx.x;  // 65536 total
    if (i < 65536) {
        h1ring[i] = f2bf(h0[i]);  // slot 0 = h1_state(-1) = h0
        h2ring[i] = 0;            // slot 0 = h2_state(-1) = 0
    }
    if (i == 0) *bar = 0u;
}

// ---------------- generic 64x256-tile bf16 GEMM (C = A @ B^T + bias) ----------------
template <int MODE, int K>
__global__ __launch_bounds__(256) void gemm_kernel(const u16* __restrict__ Asrc, const u16* __restrict__ Bmat,
                                                   const int* __restrict__ gt, const float* __restrict__ bias,
                                                   void* __restrict__ outp) {
    __shared__ uint4 AldsV[512];   // 64 x 64 bf16 = 8 KiB
    __shared__ uint4 BldsV[2048];  // 256 x 64 bf16 = 32 KiB
    char* Al = (char*)AldsV;
    char* Bl = (char*)BldsV;
    const int t = blockIdx.y;
    const int n0 = blockIdx.x << 8;
    const int tid = threadIdx.x;
    const int lane = tid & 63, wid = tid >> 6;

    f32x4 acc[4][4] = {};

    for (int k0 = 0; k0 < K; k0 += 64) {
#pragma unroll
        for (int q = 0; q < 2; ++q) {
            int c = tid + (q << 8);
            int row = c >> 3, kc = c & 7;
            const u16* src;
            if (MODE == 0) {
                int tok = gt[row * 256 + t];
                src = Asrc + (size_t)tok * 512 + (k0 + (kc << 3));
            } else {
                src = Asrc + ((size_t)((t << 6) + row) << 10) + (k0 + (kc << 3));
            }
            *(uint4*)(Al + row * 128 + ((kc ^ (row & 7)) << 4)) = *(const uint4*)src;
        }
#pragma unroll
        for (int q = 0; q < 8; ++q) {
            int c = tid + (q << 8);
            int row = c >> 3, kc = c & 7;
            *(uint4*)(Bl + row * 128 + ((kc ^ (row & 7)) << 4)) =
                *(const uint4*)(Bmat + (size_t)(n0 + row) * K + (k0 + (kc << 3)));
        }
        __syncthreads();
#pragma unroll
        for (int kb2 = 0; kb2 < 2; ++kb2) {
            bf16x8 af[4], bf[4];
#pragma unroll
            for (int mt = 0; mt < 4; ++mt) {
                int row = (mt << 4) + (lane & 15);
                int kc = (kb2 << 2) + (lane >> 4);
                af[mt] = *(const bf16x8*)(Al + row * 128 + ((kc ^ (row & 7)) << 4));
            }
#pragma unroll
            for (int nt = 0; nt < 4; ++nt) {
                int row = (wid << 6) + (nt << 4) + (lane & 15);
                int kc = (kb2 << 2) + (lane >> 4);
                bf[nt] = *(const bf16x8*)(Bl + row * 128 + ((kc ^ (row & 7)) << 4));
            }
#pragma unroll
            for (int mt = 0; mt < 4; ++mt)
#pragma unroll
                for (int nt = 0; nt < 4; ++nt)
                    acc[mt][nt] = __builtin_amdgcn_mfma_f32_16x16x32_bf16(af[mt], bf[nt], acc[mt][nt], 0, 0, 0);
        }
        __syncthreads();
    }

#pragma unroll
    for (int nt = 0; nt < 4; ++nt) {
        int n = n0 + (wid << 6) + (nt << 4) + (lane & 15);
        float bv = 0.f;
        if (MODE == 0) bv = bias[n];
        else if (n < 8000) bv = bias[n];
#pragma unroll
        for (int mt = 0; mt < 4; ++mt) {
#pragma unroll
            for (int r = 0; r < 4; ++r) {
                int ml = (mt << 4) + ((lane >> 4) << 2) + r;
                float v = acc[mt][nt][r] + bv;
                if (MODE == 0) {
                    ((u16*)outp)[((size_t)((t << 6) + ml) << 12) + n] = f2bf(v);
                } else {
                    if (n < 8000) ((float*)outp)[(size_t)(ml * 255 + t) * 8000 + n] = v;
                }
            }
        }
    }
}

// ---------------- persistent pipelined 2-layer LSTM (cooperative, fence-free) ----
// blocks 0..63  : layer1, 16 h-columns each, K=1024, computes h1_state(i) at iter i (i<=254)
// blocks 64..191: layer2, 8 h-columns each,  K=2048, computes h2_state(i-1) at iter i (i>=1)
// h-state rings: 256 slots x 128KB; slot s holds h_state(s-1). Addresses written once
// per launch -> readers may cache normally (L2 shared per XCD); writers store
// write-through via agent-scope relaxed atomic stores (sc1), no fences anywhere.
__global__ __launch_bounds__(256) void lstm_kernel(const u16* __restrict__ X1, const float* __restrict__ c0,
                                                   u16* __restrict__ h1ring, u16* __restrict__ h2ring,
                                                   u16* __restrict__ H2, const u16* __restrict__ Whh1,
                                                   const u16* __restrict__ Wih2, const u16* __restrict__ Whh2,
                                                   const float* __restrict__ b2, unsigned* __restrict__ bar) {
    __shared__ uint4 WldsV[8192];  // 128 KiB weight slice
    __shared__ u64 scr[256];       // 2 KiB repack scratch for wide coherent h stores
    char* Wb = (char*)WldsV;
    u16* scr16 = (u16*)scr;
    const int tid = threadIdx.x;
    const int lane = tid & 63, wid = tid >> 6;
    const int bid = blockIdx.x;
    const bool L1 = (bid < 64);
    const int j0 = L1 ? (bid << 4) : ((bid - 64) << 3);

    // ---- stage weights into LDS (XOR-swizzled rows) ----
    if (L1) {
#pragma unroll 8
        for (int q = 0; q < 32; ++q) {
            int c = tid + (q << 8);
            int row = c >> 7, kc = c & 127;
            int gcol = ((row >> 4) << 10) + j0 + (row & 15);
            uint4 v = *(const uint4*)(Whh1 + ((size_t)gcol << 10) + (kc << 3));
            *(uint4*)(Wb + row * 2048 + ((kc ^ (row & 7)) << 4)) = v;
        }
    } else {
#pragma unroll 8
        for (int q = 0; q < 32; ++q) {
            int c = tid + (q << 8);
            int row = c >> 8, kc = c & 255;
            int gcol = ((row >> 3) << 10) + j0 + (row & 7);
            const u16* src = (kc < 128) ? (Wih2 + ((size_t)gcol << 10) + (kc << 3))
                                        : (Whh2 + ((size_t)gcol << 10) + ((kc - 128) << 3));
            uint4 v = *(const uint4*)src;
            *(uint4*)(Wb + row * 4096 + ((kc ^ (row & 7)) << 4)) = v;
        }
    }

    float creg[4] = {0.f, 0.f, 0.f, 0.f};
    if (L1) {
        int jj = lane & 15;
#pragma unroll
        for (int r = 0; r < 4; ++r) {
            int b = (wid << 4) + ((lane >> 4) << 2) + r;
            creg[r] = c0[(b << 10) + j0 + jj];
        }
    }
    float b2v[4] = {0.f, 0.f, 0.f, 0.f};
    if (!L1 && (lane & 15) < 8) {
        int jj = lane & 7;
#pragma unroll
        for (int g = 0; g < 4; ++g) b2v[g] = b2[(g << 10) + j0 + jj];
    }
    __syncthreads();

    for (int i = 0; i < 256; ++i) {
        if (L1) {
            if (i < 255) {
                // prefetch X1 gate values (independent of h)
                u16 xv[4][4];
                {
                    int jj = lane & 15;
#pragma unroll
                    for (int r = 0; r < 4; ++r) {
                        int b = (wid << 4) + ((lane >> 4) << 2) + r;
                        const u16* xp = X1 + ((size_t)((i << 6) + b) << 12) + j0 + jj;
                        xv[0][r] = xp[0];
                        xv[1][r] = xp[1024];
                        xv[2][r] = xp[2048];
                        xv[3][r] = xp[3072];
                    }
                }
                const u16* hp = h1ring + ((size_t)i << 16);  // h1_state(i-1)
                const int arow = (wid << 4) + (lane & 15);
                const u16* ab = hp + (arow << 10) + ((lane >> 4) << 3);
                f32x4 acc[4] = {};
#pragma unroll 8
                for (int kb = 0; kb < 32; ++kb) {
                    bf16x8 a = *(const bf16x8*)(ab + (kb << 5));
#pragma unroll
                    for (int g = 0; g < 4; ++g) {
                        int row = (g << 4) + (lane & 15);
                        int kc = (kb << 2) + (lane >> 4);
                        bf16x8 bfrag = *(const bf16x8*)(Wb + row * 2048 + ((kc ^ (row & 7)) << 4));
                        acc[g] = __builtin_amdgcn_mfma_f32_16x16x32_bf16(a, bfrag, acc[g], 0, 0, 0);
                    }
                }
                int jj = lane & 15;
#pragma unroll
                for (int r = 0; r < 4; ++r) {
                    int b = (wid << 4) + ((lane >> 4) << 2) + r;
                    float gi = acc[0][r] + bf2f(xv[0][r]);
                    float gf = acc[1][r] + bf2f(xv[1][r]);
                    float gg = acc[2][r] + bf2f(xv[2][r]);
                    float go = acc[3][r] + bf2f(xv[3][r]);
                    float cc = sigm(gf) * creg[r] + sigm(gi) * tanha(gg);
                    creg[r] = cc;
                    scr16[(b << 4) + jj] = f2bf(sigm(go) * tanha(cc));
                }
            }
        } else {
            if (i >= 1) {
                const u16* hp1 = h1ring + ((size_t)i << 16);        // h1_state(i-1)
                const u16* hp2 = h2ring + ((size_t)(i - 1) << 16);  // h2_state(i-2)
                const int arow = (wid << 4) + (lane & 15);
                const u16* ab1 = hp1 + (arow << 10) + ((lane >> 4) << 3);
                const u16* ab2 = hp2 + (arow << 10) + ((lane >> 4) << 3);
                f32x4 acc[2] = {};
#pragma unroll 8
                for (int kb = 0; kb < 32; ++kb) {
                    bf16x8 a = *(const bf16x8*)(ab1 + (kb << 5));
#pragma unroll
                    for (int nt = 0; nt < 2; ++nt) {
                        int row = (nt << 4) + (lane & 15);
                        int kc = (kb << 2) + (lane >> 4);
                        bf16x8 bfrag = *(const bf16x8*)(Wb + row * 4096 + ((kc ^ (row & 7)) << 4));
                        acc[nt] = __builtin_amdgcn_mfma_f32_16x16x32_bf16(a, bfrag, acc[nt], 0, 0, 0);
                    }
                }
#pragma unroll 8
                for (int kb = 32; kb < 64; ++kb) {
                    bf16x8 a = *(const bf16x8*)(ab2 + ((kb - 32) << 5));
#pragma unroll
                    for (int nt = 0; nt < 2; ++nt) {
                        int row = (nt << 4) + (lane & 15);
                        int kc = (kb << 2) + (lane >> 4);
                        bf16x8 bfrag = *(const bf16x8*)(Wb + row * 4096 + ((kc ^ (row & 7)) << 4));
                        acc[nt] = __builtin_amdgcn_mfma_f32_16x16x32_bf16(a, bfrag, acc[nt], 0, 0, 0);
                    }
                }
                int s = i - 1;
#pragma unroll
                for (int r = 0; r < 4; ++r) {
                    float v0 = acc[0][r], v1 = acc[1][r];
                    float p0 = __shfl_xor(v0, 8, 64);
                    float p1 = __shfl_xor(v1, 8, 64);
                    if ((lane & 15) < 8) {
                        int jj = lane & 7;
                        int b = (wid << 4) + ((lane >> 4) << 2) + r;
                        float gi = v0 + b2v[0];
                        float gf = p0 + b2v[1];
                        float gg = v1 + b2v[2];
                        float go = p1 + b2v[3];
                        float cc = sigm(gf) * creg[r] + sigm(gi) * tanha(cc = 0.f), dummy;  // placeholder avoided
                        (void)dummy;
                        // (recompute cleanly)
                        cc = sigm(gf) * creg[r] + sigm(gi) * tanha(gg);
                        creg[r] = cc;
                        u16 hb = f2bf(sigm(go) * tanha(cc));
                        scr16[(b << 3) + jj] = hb;
                        H2[((size_t)((s << 6) + b) << 10) + j0 + jj] = hb;  // plain cached store
                    }
                }
            }
        }
        __syncthreads();
        // wide write-through (sc1) h-state store from LDS scratch
        if (L1) {
            if (i < 255) {
                u64 v = scr[tid];
                int b = tid >> 2, c4 = tid & 3;
                u16* dst = h1ring + (((size_t)(i + 1)) << 16) + (b << 10) + j0 + (c4 << 2);
                __hip_atomic_store((u64*)dst, v, __ATOMIC_RELAXED, __HIP_MEMORY_SCOPE_AGENT);
            }
        } else {
            if (i >= 1 && i < 255 && tid < 128) {
                u64 v = scr[tid];
                int b = tid >> 1, c4 = tid & 1;
                u16* dst = h2ring + (((size_t)i) << 16) + (b << 10) + j0 + (c4 << 2);
                __hip_atomic_store((u64*)dst, v, __ATOMIC_RELAXED, __HIP_MEMORY_SCOPE_AGENT);
            }
        }
        asm volatile("s_waitcnt vmcnt(0)" ::: "memory");
        if (i < 255) grid_bar(bar, (unsigned)(NBLK * (i + 1)));
    }
}

// ---------------- per-row log-softmax, in-place on d_out ----------------
__global__ __launch_bounds__(256) void lsm_kernel(float* __restrict__ out) {
    float* p = out + (size_t)blockIdx.x * 8000;
    const int tid = threadIdx.x;
    float4 v[8];
    float mx = -3.0e38f;
#pragma unroll
    for (int q = 0; q < 8; ++q) {
        int vi = tid + (q << 8);
        if (vi < 2000) {
            v[q] = *((const float4*)p + vi);
            mx = fmaxf(mx, fmaxf(fmaxf(v[q].x, v[q].y), fmaxf(v[q].z, v[q].w)));
        }
    }
#pragma unroll
    for (int o = 32; o >= 1; o >>= 1) mx = fmaxf(mx, __shfl_xor(mx, o, 64));
    __shared__ float red[8];
    if ((tid & 63) == 0) red[tid >> 6] = mx;
    __syncthreads();
    mx = fmaxf(fmaxf(red[0], red[1]), fmaxf(red[2], red[3]));
    float s = 0.f;
#pragma unroll
    for (int q = 0; q < 8; ++q) {
        int vi = tid + (q << 8);
        if (vi < 2000)
            s += __expf(v[q].x - mx) + __expf(v[q].y - mx) + __expf(v[q].z - mx) + __expf(v[q].w - mx);
    }
#pragma unroll
    for (int o = 32; o >= 1; o >>= 1) s += __shfl_xor(s, o, 64);
    if ((tid & 63) == 0) red[4 + (tid >> 6)] = s;
    __syncthreads();
    float lz = mx + logf(red[4] + red[5] + red[6] + red[7]);
#pragma unroll
    for (int q = 0; q < 8; ++q) {
        int vi = tid + (q << 8);
        if (vi < 2000) {
            float4 o4;
            o4.x = v[q].x - lz; o4.y = v[q].y - lz; o4.z = v[q].z - lz; o4.w = v[q].w - lz;
            *((float4*)p + vi) = o4;
        }
    }
}

// ---------------- host launch ----------------
extern "C" void kernel_launch(void* const* d_in, const int* in_sizes, int n_in,
                              void* d_out, int out_size, void* d_ws, size_t ws_size,
                              hipStream_t stream) {
    const int* gt = (const int*)d_in[0];
    const float* h0 = (const float*)d_in[1];
    const float* c0 = (const float*)d_in[2];
    const float* emb = (const float*)d_in[3];
    const float* Wih1 = (const float*)d_in[4];
    const float* Whh1 = (const float*)d_in[5];
    const float* bih1 = (const float*)d_in[6];
    const float* bhh1 = (const float*)d_in[7];
    const float* Wih2 = (const float*)d_in[8];
    const float* Whh2 = (const float*)d_in[9];
    const float* bih2 = (const float*)d_in[10];
    const float* bhh2 = (const float*)d_in[11];
    const float* Wout = (const float*)d_in[12];
    const float* bout = (const float*)d_in[13];

    char* w = (char*)d_ws;
    size_t off = 0;
    auto alloc = [&](size_t bytes) -> void* {
        void* p = (void*)(w + off);
        off = (off + bytes + 255) & ~(size_t)255;
        return p;
    };
    unsigned* bar = (unsigned*)alloc(256);
    float* b1 = (float*)alloc(4096 * 4);
    float* b2 = (float*)alloc(4096 * 4);
    u16* embB = (u16*)alloc((size_t)8000 * 512 * 2);
    u16* Wih1B = (u16*)alloc((size_t)4096 * 512 * 2);
    u16* Whh1B = (u16*)alloc((size_t)4096 * 1024 * 2);
    u16* Wih2B = (u16*)alloc((size_t)4096 * 1024 * 2);
    u16* Whh2B = (u16*)alloc((size_t)4096 * 1024 * 2);
    u16* WoutB = (u16*)alloc((size_t)8192 * 1024 * 2);
    u16* H2 = (u16*)alloc((size_t)16320 * 1024 * 2);

    // d_out (522 MB) scratch layout: X1 at 0 (134 MB), h rings at 136/168 MB.
    // All of it is dead by the time phase C overwrites d_out.
    u16* X1 = (u16*)d_out;
    u16* h1ring = (u16*)((char*)d_out + (size_t)136 * 1024 * 1024);  // 256 x 64KiB*2
    u16* h2ring = (u16*)((char*)d_out + (size_t)168 * 1024 * 1024);

    auto cvtN = [&](const float* s, u16* d, long long n) {
        unsigned blocks = (unsigned)((n / 4 + 255) / 256);
        cvt_kernel<<<blocks, 256, 0, stream>>>(s, d, n);
    };
    cvtN(emb, embB, (long long)8000 * 512);
    cvtN(Wih1, Wih1B, (long long)4096 * 512);
    cvtN(Whh1, Whh1B, (long long)4096 * 1024);
    cvtN(Wih2, Wih2B, (long long)4096 * 1024);
    cvtN(Whh2, Whh2B, (long long)4096 * 1024);
    cvt_wout_kernel<<<8192, 256, 0, stream>>>(Wout, WoutB);
    badd_kernel<<<16, 256, 0, stream>>>(bih1, bhh1, b1, 4096);
    badd_kernel<<<16, 256, 0, stream>>>(bih2, bhh2, b2, 4096);
    init_kernel<<<256, 256, 0, stream>>>(h0, h1ring, h2ring, bar);

    // phase A: X1 = emb[gt] @ Wih1^T + b1  (bf16, into d_out scratch)
    gemm_kernel<0, 512><<<dim3(16, 255), 256, 0, stream>>>(embB, Wih1B, gt, b1, (void*)X1);

    // phase B: persistent pipelined recurrence
    {
        void* args[] = {(void*)&X1, (void*)&c0, (void*)&h1ring, (void*)&h2ring, (void*)&H2,
                        (void*)&Whh1B, (void*)&Wih2B, (void*)&Whh2B, (void*)&b2, (void*)&bar};
        (void)hipLaunchCooperativeKernel(reinterpret_cast<const void*>(&lstm_kernel),
                                         dim3(NBLK), dim3(256), args, 0, stream);
    }

    // phase C: logits = H2 @ Wout^T + bout  (fp32 into d_out)
    gemm_kernel<1, 1024><<<dim3(32, 255), 256, 0, stream>>>(H2, WoutB, nullptr, bout, d_out);

    // log-softmax in place
    lsm_kernel<<<16320, 256, 0, stream>>>((float*)d_out);
}